// Round 1
// baseline (348.076 us; speedup 1.0000x reference)
//
#include <hip/hip_runtime.h>

#define NROWS 8192
#define NHALF 4096
#define DIM   256
#define BM    128
#define BN    128
#define BK    16

// Row i of the implicit concat([source, target]) matrix.
__device__ __forceinline__ const float* side_base(const float* src, const float* tgt, int row) {
    return (row < NHALF) ? (src + (size_t)row * DIM)
                         : (tgt + (size_t)(row - NHALF) * DIM);
}

// Pass 1: per-row sum-of-squares sq[i] (fp32), plus fp64 totals:
//   sumsq = sum_i sq[i], colsum[d] = sum_i total[i][d]
// One wave (64 lanes) per row: lane l holds cols 4l..4l+3 as a float4.
__global__ __launch_bounds__(256) void rowstats_kernel(
        const float* __restrict__ src, const float* __restrict__ tgt,
        float* __restrict__ sq, double* __restrict__ colsum, double* __restrict__ sumsq)
{
    int lane   = threadIdx.x & 63;
    int wave   = blockIdx.x * (blockDim.x >> 6) + (threadIdx.x >> 6);
    int nwaves = gridDim.x * (blockDim.x >> 6);
    double cs0 = 0, cs1 = 0, cs2 = 0, cs3 = 0, lss = 0;
    for (int r = wave; r < NROWS; r += nwaves) {
        const float* p = side_base(src, tgt, r);
        float4 v = *(const float4*)(p + 4 * lane);
        cs0 += (double)v.x; cs1 += (double)v.y; cs2 += (double)v.z; cs3 += (double)v.w;
        float d = v.x * v.x + v.y * v.y + v.z * v.z + v.w * v.w;
        #pragma unroll
        for (int off = 32; off > 0; off >>= 1) d += __shfl_xor(d, off);
        if (lane == 0) { sq[r] = d; lss += (double)d; }
    }
    atomicAdd(&colsum[4 * lane + 0], cs0);
    atomicAdd(&colsum[4 * lane + 1], cs1);
    atomicAdd(&colsum[4 * lane + 2], cs2);
    atomicAdd(&colsum[4 * lane + 3], cs3);
    if (lane == 0) atomicAdd(sumsq, lss);
}

// Pass 2 (tiny): bandwidth via the algebraic identity, then the 5 kernel
// constants c5[m] = -1 / (bw * 2^m) for use with __expf.
__global__ void bw_kernel(const double* __restrict__ colsum,
                          const double* __restrict__ sumsq, float* __restrict__ c5)
{
    __shared__ double red[256];
    int t = threadIdx.x;
    double c = colsum[t];
    red[t] = c * c;
    __syncthreads();
    for (int s = 128; s > 0; s >>= 1) { if (t < s) red[t] += red[t + s]; __syncthreads(); }
    if (t == 0) {
        double ns = (double)NROWS;
        // sum(dist) = 2*ns*sum_i sq_i - 2*||colsum||^2
        double sumdist = 2.0 * ns * sumsq[0] - 2.0 * red[0];
        double bw = sumdist / (ns * ns - ns);
        bw = bw / 4.0;  // KERNEL_MUL^(KERNEL_NUM//2) = 2^2
        #pragma unroll
        for (int m = 0; m < 5; ++m)
            c5[m] = (float)(-1.0 / (bw * (double)(1 << m)));
    }
}

// Pass 3: tiled implicit GEMM (total @ total^T) with fused MMD epilogue.
// 128x128 tile / 256 threads / 8x8 microtile / BK=16. Upper-triangular
// blocks only (bx >= by); off-diagonal blocks weighted 2x (symmetry).
__global__ __launch_bounds__(256) void mmd_main_kernel(
        const float* __restrict__ src, const float* __restrict__ tgt,
        const float* __restrict__ sq, const float* __restrict__ c5,
        float* __restrict__ partials)
{
    __shared__ float As[BK][BM + 4];
    __shared__ float Bs[BK][BN + 4];
    __shared__ float red[256];

    int bx = blockIdx.x, by = blockIdx.y;
    int bid = by * gridDim.x + bx;
    int t = threadIdx.x;
    if (bx < by) {                 // symmetric half: skip, but leave a clean 0
        if (t == 0) partials[bid] = 0.f;
        return;
    }
    int rowBase = by * BM, colBase = bx * BN;
    const float* Ab = side_base(src, tgt, rowBase);  // tiles never straddle n=4096
    const float* Bb = side_base(src, tgt, colBase);

    int tx = t & 15, ty = t >> 4;
    int lr = t >> 2;          // 0..63: row-within-tile for loads
    int lk = (t & 3) << 2;    // 0,4,8,12: k-quad for loads

    float acc[8][8];
    #pragma unroll
    for (int i = 0; i < 8; ++i)
        #pragma unroll
        for (int j = 0; j < 8; ++j) acc[i][j] = 0.f;

    for (int kt = 0; kt < DIM; kt += BK) {
        float4 va0 = *(const float4*)(Ab + (size_t)lr * DIM + kt + lk);
        float4 va1 = *(const float4*)(Ab + (size_t)(lr + 64) * DIM + kt + lk);
        float4 vb0 = *(const float4*)(Bb + (size_t)lr * DIM + kt + lk);
        float4 vb1 = *(const float4*)(Bb + (size_t)(lr + 64) * DIM + kt + lk);
        __syncthreads();   // previous iteration's reads complete before overwrite
        As[lk + 0][lr] = va0.x; As[lk + 1][lr] = va0.y; As[lk + 2][lr] = va0.z; As[lk + 3][lr] = va0.w;
        As[lk + 0][lr + 64] = va1.x; As[lk + 1][lr + 64] = va1.y; As[lk + 2][lr + 64] = va1.z; As[lk + 3][lr + 64] = va1.w;
        Bs[lk + 0][lr] = vb0.x; Bs[lk + 1][lr] = vb0.y; Bs[lk + 2][lr] = vb0.z; Bs[lk + 3][lr] = vb0.w;
        Bs[lk + 0][lr + 64] = vb1.x; Bs[lk + 1][lr + 64] = vb1.y; Bs[lk + 2][lr + 64] = vb1.z; Bs[lk + 3][lr + 64] = vb1.w;
        __syncthreads();
        #pragma unroll
        for (int k = 0; k < BK; ++k) {
            float4 a0 = *(const float4*)&As[k][ty * 4];
            float4 a1 = *(const float4*)&As[k][ty * 4 + 64];
            float4 b0 = *(const float4*)&Bs[k][tx * 4];
            float4 b1 = *(const float4*)&Bs[k][tx * 4 + 64];
            float a[8] = {a0.x, a0.y, a0.z, a0.w, a1.x, a1.y, a1.z, a1.w};
            float b[8] = {b0.x, b0.y, b0.z, b0.w, b1.x, b1.y, b1.z, b1.w};
            #pragma unroll
            for (int i = 0; i < 8; ++i)
                #pragma unroll
                for (int j = 0; j < 8; ++j)
                    acc[i][j] += a[i] * b[j];
        }
    }

    // Fused epilogue: dist -> 5 exponentials -> per-thread partial.
    float c0 = c5[0], c1 = c5[1], c2v = c5[2], c3 = c5[3], c4 = c5[4];
    float sqa[8], sqb[8];
    #pragma unroll
    for (int i = 0; i < 8; ++i) sqa[i] = sq[rowBase + ty * 4 + (i & 3) + (i >> 2) * 64];
    #pragma unroll
    for (int j = 0; j < 8; ++j) sqb[j] = sq[colBase + tx * 4 + (j & 3) + (j >> 2) * 64];

    float psum = 0.f;
    #pragma unroll
    for (int i = 0; i < 8; ++i) {
        #pragma unroll
        for (int j = 0; j < 8; ++j) {
            float dist = sqa[i] + sqb[j] - 2.f * acc[i][j];
            psum += __expf(dist * c0) + __expf(dist * c1) + __expf(dist * c2v)
                  + __expf(dist * c3) + __expf(dist * c4);
        }
    }

    red[t] = psum;
    __syncthreads();
    for (int s = 128; s > 0; s >>= 1) {
        if (t < s) red[t] += red[t + s];
        __syncthreads();
    }
    if (t == 0) {
        float sign = ((rowBase < NHALF) == (colBase < NHALF)) ? 1.f : -1.f;
        float w = (bx == by) ? 1.f : 2.f;   // symmetry weight
        partials[bid] = sign * w * red[0];
    }
}

// Pass 4: fp64 reduction of block partials -> final scalar.
__global__ void finalize_kernel(const float* __restrict__ partials, int n,
                                float* __restrict__ out)
{
    __shared__ double red[256];
    int t = threadIdx.x;
    double s = 0;
    for (int i = t; i < n; i += 256) s += (double)partials[i];
    red[t] = s;
    __syncthreads();
    for (int k = 128; k > 0; k >>= 1) { if (t < k) red[t] += red[t + k]; __syncthreads(); }
    if (t == 0) {
        double nn = (double)NHALF;
        out[0] = (float)(red[0] / 5.0 / (2.0 * nn * nn));
    }
}

extern "C" void kernel_launch(void* const* d_in, const int* in_sizes, int n_in,
                              void* d_out, int out_size, void* d_ws, size_t ws_size,
                              hipStream_t stream) {
    const float* src = (const float*)d_in[0];
    const float* tgt = (const float*)d_in[1];
    float* out = (float*)d_out;
    char* ws = (char*)d_ws;

    // ws layout:
    //   [0,      2048)  double colsum[256]
    //   [2048,   2056)  double sumsq
    //   [2056,   2080)  float  c5[5] (+pad)
    //   [4096,  36864)  float  sq[8192]
    //   [36864, 53248)  float  partials[4096]
    double* colsum   = (double*)ws;
    double* sumsq    = (double*)(ws + 2048);
    float*  c5       = (float*)(ws + 2056);
    float*  sq       = (float*)(ws + 4096);
    float*  partials = (float*)(ws + 36864);

    hipMemsetAsync(ws, 0, 2056, stream);   // zero colsum + sumsq (accumulated atomically)

    rowstats_kernel<<<16, 256, 0, stream>>>(src, tgt, sq, colsum, sumsq);
    bw_kernel<<<1, 256, 0, stream>>>(colsum, sumsq, c5);

    dim3 grid(NROWS / BN, NROWS / BM);
    mmd_main_kernel<<<grid, 256, 0, stream>>>(src, tgt, sq, c5, partials);

    finalize_kernel<<<1, 256, 0, stream>>>(partials, (NROWS / BM) * (NROWS / BN), out);
}

// Round 2
// 169.608 us; speedup vs baseline: 2.0522x; 2.0522x over previous
//
#include <hip/hip_runtime.h>

#define NROWS 8192
#define NHALF 4096
#define DIM   256
#define NB_PREP 256

typedef __attribute__((ext_vector_type(8))) __bf16 bf16x8;
typedef __attribute__((ext_vector_type(4))) __bf16 bf16x4;
typedef __attribute__((ext_vector_type(4))) float  f32x4;

__device__ __forceinline__ const float* side_base(const float* src, const float* tgt, int row) {
    return (row < NHALF) ? (src + (size_t)row * DIM)
                         : (tgt + (size_t)(row - NHALF) * DIM);
}

// Pass 1: fp32 -> (hi,lo) bf16 split arrays H,L; per-row sumsq sq[] (fp32);
// per-block column-sum partials + sumsq partials for the bandwidth identity.
__global__ __launch_bounds__(256) void prep_kernel(
        const float* __restrict__ src, const float* __restrict__ tgt,
        __bf16* __restrict__ H, __bf16* __restrict__ L,
        float* __restrict__ sq, float* __restrict__ colpart, float* __restrict__ sqpart)
{
    int t = threadIdx.x;
    int lane = t & 63;
    int w = t >> 6;
    int wave = blockIdx.x * 4 + w;
    float cs0 = 0, cs1 = 0, cs2 = 0, cs3 = 0;
    double lss = 0.0;
    for (int r = wave; r < NROWS; r += NB_PREP * 4) {
        const float* p = side_base(src, tgt, r);
        float4 v = *(const float4*)(p + 4 * lane);
        cs0 += v.x; cs1 += v.y; cs2 += v.z; cs3 += v.w;
        __bf16 hx = (__bf16)v.x, hy = (__bf16)v.y, hz = (__bf16)v.z, hw = (__bf16)v.w;
        bf16x4 hv = {hx, hy, hz, hw};
        bf16x4 lv = {(__bf16)(v.x - (float)hx), (__bf16)(v.y - (float)hy),
                     (__bf16)(v.z - (float)hz), (__bf16)(v.w - (float)hw)};
        *(bf16x4*)(H + (size_t)r * DIM + 4 * lane) = hv;
        *(bf16x4*)(L + (size_t)r * DIM + 4 * lane) = lv;
        float d = v.x * v.x + v.y * v.y + v.z * v.z + v.w * v.w;
        #pragma unroll
        for (int off = 32; off > 0; off >>= 1) d += __shfl_xor(d, off);
        if (lane == 0) { sq[r] = d; lss += (double)d; }
    }
    __shared__ float csh[4][256];
    __shared__ double ssh[4];
    csh[w][4 * lane + 0] = cs0; csh[w][4 * lane + 1] = cs1;
    csh[w][4 * lane + 2] = cs2; csh[w][4 * lane + 3] = cs3;
    if (lane == 0) ssh[w] = lss;
    __syncthreads();
    colpart[blockIdx.x * 256 + t] = csh[0][t] + csh[1][t] + csh[2][t] + csh[3][t];
    if (t == 0) sqpart[blockIdx.x] = (float)(ssh[0] + ssh[1] + ssh[2] + ssh[3]);
}

// Pass 2 (tiny): bandwidth via sum(dist) = 2*ns*sumsq - 2*||colsum||^2 (fp64),
// then the single exp2 constant q = log2(e) / (16*bw).
__global__ void bw_kernel(const float* __restrict__ colpart,
                          const float* __restrict__ sqpart, float* __restrict__ qconst)
{
    __shared__ double red[256], red2[256];
    int t = threadIdx.x;
    double s = 0;
    for (int b = 0; b < NB_PREP; ++b) s += (double)colpart[b * 256 + t];
    red[t] = s * s;
    red2[t] = (double)sqpart[t];   // NB_PREP == 256
    __syncthreads();
    for (int k = 128; k > 0; k >>= 1) {
        if (t < k) { red[t] += red[t + k]; red2[t] += red2[t + k]; }
        __syncthreads();
    }
    if (t == 0) {
        double ns = (double)NROWS;
        double sumdist = 2.0 * ns * red2[0] - 2.0 * red[0];
        double bw = sumdist / (ns * ns - ns) / 4.0;   // KERNEL_MUL^(KERNEL_NUM//2)=4
        qconst[0] = (float)(1.4426950408889634 / (16.0 * bw));
    }
}

// Pass 3: bf16 MFMA Gram GEMM, 3 split passes (hi*hi + hi*lo + lo*hi), with
// fused MMD epilogue. 128x128 tile / 4 waves (2x2) / 16x16x32 MFMA / BK=64.
// LDS tiles XOR-swizzled ((row&7)<<4) via pre-swizzled global_load_lds source.
__global__ __launch_bounds__(256) void mmd_main_kernel(
        const __bf16* __restrict__ H, const __bf16* __restrict__ L,
        const float* __restrict__ sq, const float* __restrict__ qc,
        float* __restrict__ partials)
{
    __shared__ alignas(16) char lds[32768];   // A tile 16KB | B tile 16KB
    __shared__ float red[256];

    int wg = blockIdx.x;
    int swz = (wg & 7) * 512 + (wg >> 3);     // XCD-contiguous chunks (4096%8==0)
    int by = swz >> 6, bx = swz & 63;
    int t = threadIdx.x;
    if (bx < by) { if (t == 0) partials[swz] = 0.f; return; }

    int rowBase = by * 128, colBase = bx * 128;
    int lane = t & 63, w = t >> 6;
    int wr = w >> 1, wc = w & 1;

    f32x4 acc[4][4];
    #pragma unroll
    for (int m = 0; m < 4; ++m)
        #pragma unroll
        for (int n = 0; n < 4; ++n) acc[m][n] = (f32x4)0.f;

    for (int ks = 0; ks < 12; ++ks) {
        int pass = ks >> 2, kc = ks & 3;
        const __bf16* Am = (pass == 2) ? L : H;   // A: hi, hi, lo
        const __bf16* Bm = (pass == 1) ? L : H;   // B: hi, lo, hi
        __syncthreads();   // previous step's ds_reads done before overwrite
        #pragma unroll
        for (int q = 0; q < 4; ++q) {
            int p = w * 4096 + q * 1024 + lane * 16;     // linear LDS byte offset
            int row = p >> 7;                            // 128B per row (64 bf16)
            int lcol = (p & 127) ^ ((row & 7) << 4);     // inverse-swizzled source col
            const char* ga = (const char*)Am + ((size_t)(rowBase + row) * 512 + kc * 128 + lcol);
            const char* gb = (const char*)Bm + ((size_t)(colBase + row) * 512 + kc * 128 + lcol);
            __builtin_amdgcn_global_load_lds(
                (const __attribute__((address_space(1))) void*)ga,
                (__attribute__((address_space(3))) void*)(lds + p), 16, 0, 0);
            __builtin_amdgcn_global_load_lds(
                (const __attribute__((address_space(1))) void*)gb,
                (__attribute__((address_space(3))) void*)(lds + 16384 + p), 16, 0, 0);
        }
        __syncthreads();   // compiler drains vmcnt(0) before barrier
        #pragma unroll
        for (int kk = 0; kk < 2; ++kk) {
            int kbyte = kk * 64 + (lane >> 4) * 16;
            bf16x8 af[4], bf[4];
            #pragma unroll
            for (int m = 0; m < 4; ++m) {
                int row = wr * 64 + m * 16 + (lane & 15);
                int off = ((row << 7) + kbyte) ^ ((row & 7) << 4);
                af[m] = *(const bf16x8*)(lds + off);
            }
            #pragma unroll
            for (int n = 0; n < 4; ++n) {
                int row = wc * 64 + n * 16 + (lane & 15);
                int off = ((row << 7) + kbyte) ^ ((row & 7) << 4);
                bf[n] = *(const bf16x8*)(lds + 16384 + off);
            }
            #pragma unroll
            for (int m = 0; m < 4; ++m)
                #pragma unroll
                for (int n = 0; n < 4; ++n)
                    acc[m][n] = __builtin_amdgcn_mfma_f32_16x16x32_bf16(
                        af[m], bf[n], acc[m][n], 0, 0, 0);
        }
    }

    // Fused epilogue: e4 = exp2(-dist*q); e3..e0 by repeated squaring.
    float q = qc[0], twoq = 2.f * q;
    int rsub = (lane >> 4) * 4, csub = lane & 15;
    float nqa[4][4], qb[4];
    #pragma unroll
    for (int m = 0; m < 4; ++m)
        #pragma unroll
        for (int r = 0; r < 4; ++r)
            nqa[m][r] = -q * sq[rowBase + wr * 64 + m * 16 + rsub + r];
    #pragma unroll
    for (int n = 0; n < 4; ++n)
        qb[n] = q * sq[colBase + wc * 64 + n * 16 + csub];

    float psum = 0.f;
    #pragma unroll
    for (int m = 0; m < 4; ++m) {
        #pragma unroll
        for (int n = 0; n < 4; ++n) {
            #pragma unroll
            for (int r = 0; r < 4; ++r) {
                float arg = fmaf(acc[m][n][r], twoq, nqa[m][r] - qb[n]); // = -dist*q*log2e... (q includes log2e)
                float e4 = __builtin_amdgcn_exp2f(arg);
                float e3 = e4 * e4, e2 = e3 * e3, e1 = e2 * e2, e0 = e1 * e1;
                psum += ((e4 + e3) + (e2 + e1)) + e0;
            }
        }
    }

    red[t] = psum;
    __syncthreads();
    for (int s = 128; s > 0; s >>= 1) {
        if (t < s) red[t] += red[t + s];
        __syncthreads();
    }
    if (t == 0) {
        float sign = ((rowBase < NHALF) == (colBase < NHALF)) ? 1.f : -1.f;
        float wgt = (bx == by) ? 1.f : 2.f;
        partials[swz] = sign * wgt * red[0];
    }
}

// Pass 4: fp64 reduction of block partials -> final scalar.
__global__ void finalize_kernel(const float* __restrict__ partials, int n,
                                float* __restrict__ out)
{
    __shared__ double red[256];
    int t = threadIdx.x;
    double s = 0;
    for (int i = t; i < n; i += 256) s += (double)partials[i];
    red[t] = s;
    __syncthreads();
    for (int k = 128; k > 0; k >>= 1) { if (t < k) red[t] += red[t + k]; __syncthreads(); }
    if (t == 0) {
        double nn = (double)NHALF;
        out[0] = (float)(red[0] / 5.0 / (2.0 * nn * nn));
    }
}

extern "C" void kernel_launch(void* const* d_in, const int* in_sizes, int n_in,
                              void* d_out, int out_size, void* d_ws, size_t ws_size,
                              hipStream_t stream) {
    const float* src = (const float*)d_in[0];
    const float* tgt = (const float*)d_in[1];
    float* out = (float*)d_out;
    char* ws = (char*)d_ws;

    // ws layout (~8.6 MB total):
    float*  colpart  = (float*)(ws + 0);        // 256*256*4 = 256 KB
    float*  sqpart   = (float*)(ws + 262144);   // 256*4
    float*  qconst   = (float*)(ws + 263168);   // 4
    float*  sq       = (float*)(ws + 264192);   // 8192*4 = 32 KB
    float*  partials = (float*)(ws + 297984);   // 4096*4 = 16 KB
    __bf16* H        = (__bf16*)(ws + 524288);  // 8192*256*2 = 4 MB
    __bf16* L        = (__bf16*)(ws + 4718592); // 4 MB

    prep_kernel<<<NB_PREP, 256, 0, stream>>>(src, tgt, H, L, sq, colpart, sqpart);
    bw_kernel<<<1, 256, 0, stream>>>(colpart, sqpart, qconst);
    mmd_main_kernel<<<4096, 256, 0, stream>>>(H, L, sq, qconst, partials);
    finalize_kernel<<<1, 256, 0, stream>>>(partials, 4096, out);
}

// Round 3
// 110.603 us; speedup vs baseline: 3.1471x; 1.5335x over previous
//
#include <hip/hip_runtime.h>

#define NROWS 8192
#define NHALF 4096
#define DIM   256
#define NB_PREP 256
#define NTILES  64            // 8192 / 128
#define NBLK    2080          // NTILES*(NTILES+1)/2 upper-triangular blocks

typedef __attribute__((ext_vector_type(8))) __bf16 bf16x8;
typedef __attribute__((ext_vector_type(4))) __bf16 bf16x4;
typedef __attribute__((ext_vector_type(4))) float  f32x4;

__device__ __forceinline__ const float* side_base(const float* src, const float* tgt, int row) {
    return (row < NHALF) ? (src + (size_t)row * DIM)
                         : (tgt + (size_t)(row - NHALF) * DIM);
}

// Pass 1: fp32 -> (hi,lo) bf16 split arrays H,L; per-row sumsq sq[] (fp32);
// per-block column-sum partials + sumsq partials for the bandwidth identity.
__global__ __launch_bounds__(256) void prep_kernel(
        const float* __restrict__ src, const float* __restrict__ tgt,
        __bf16* __restrict__ H, __bf16* __restrict__ L,
        float* __restrict__ sq, float* __restrict__ colpart, float* __restrict__ sqpart)
{
    int t = threadIdx.x;
    int lane = t & 63;
    int w = t >> 6;
    int wave = blockIdx.x * 4 + w;
    float cs0 = 0, cs1 = 0, cs2 = 0, cs3 = 0;
    double lss = 0.0;
    for (int r = wave; r < NROWS; r += NB_PREP * 4) {
        const float* p = side_base(src, tgt, r);
        float4 v = *(const float4*)(p + 4 * lane);
        cs0 += v.x; cs1 += v.y; cs2 += v.z; cs3 += v.w;
        __bf16 hx = (__bf16)v.x, hy = (__bf16)v.y, hz = (__bf16)v.z, hw = (__bf16)v.w;
        bf16x4 hv = {hx, hy, hz, hw};
        bf16x4 lv = {(__bf16)(v.x - (float)hx), (__bf16)(v.y - (float)hy),
                     (__bf16)(v.z - (float)hz), (__bf16)(v.w - (float)hw)};
        *(bf16x4*)(H + (size_t)r * DIM + 4 * lane) = hv;
        *(bf16x4*)(L + (size_t)r * DIM + 4 * lane) = lv;
        float d = v.x * v.x + v.y * v.y + v.z * v.z + v.w * v.w;
        #pragma unroll
        for (int off = 32; off > 0; off >>= 1) d += __shfl_xor(d, off);
        if (lane == 0) { sq[r] = d; lss += (double)d; }
    }
    __shared__ float csh[4][256];
    __shared__ double ssh[4];
    csh[w][4 * lane + 0] = cs0; csh[w][4 * lane + 1] = cs1;
    csh[w][4 * lane + 2] = cs2; csh[w][4 * lane + 3] = cs3;
    if (lane == 0) ssh[w] = lss;
    __syncthreads();
    colpart[blockIdx.x * 256 + t] = csh[0][t] + csh[1][t] + csh[2][t] + csh[3][t];
    if (t == 0) sqpart[blockIdx.x] = (float)(ssh[0] + ssh[1] + ssh[2] + ssh[3]);
}

// Pass 2 (tiny): bandwidth via sum(dist) = 2*ns*sumsq - 2*||colsum||^2 (fp64),
// then the single exp2 constant q = log2(e) / (16*bw).
__global__ void bw_kernel(const float* __restrict__ colpart,
                          const float* __restrict__ sqpart, float* __restrict__ qconst)
{
    __shared__ double red[256], red2[256];
    int t = threadIdx.x;
    double s = 0;
    for (int b = 0; b < NB_PREP; ++b) s += (double)colpart[b * 256 + t];
    red[t] = s * s;
    red2[t] = (double)sqpart[t];   // NB_PREP == 256
    __syncthreads();
    for (int k = 128; k > 0; k >>= 1) {
        if (t < k) { red[t] += red[t + k]; red2[t] += red2[t + k]; }
        __syncthreads();
    }
    if (t == 0) {
        double ns = (double)NROWS;
        double sumdist = 2.0 * ns * red2[0] - 2.0 * red[0];
        double bw = sumdist / (ns * ns - ns) / 4.0;   // KERNEL_MUL^(KERNEL_NUM//2)=4
        qconst[0] = (float)(1.4426950408889634 / (16.0 * bw));
    }
}

__device__ __forceinline__ int tri_cum(int b) {   // # tiles before row b
    return b * NTILES - ((b * (b - 1)) >> 1);
}

// Pass 3: bf16 MFMA Gram GEMM, 3 split passes (hi*hi + hi*lo + lo*hi), with
// fused MMD epilogue. 128x128 tile / 4 waves (2x2) / 16x16x32 MFMA / BK=64.
// Exactly NBLK upper-triangular blocks launched; rank is XCD-swizzled
// (2080 = 8*260) so each XCD gets an equal, contiguous triangle sweep.
__global__ __launch_bounds__(256) void mmd_main_kernel(
        const __bf16* __restrict__ H, const __bf16* __restrict__ L,
        const float* __restrict__ sq, const float* __restrict__ qc,
        float* __restrict__ partials)
{
    __shared__ alignas(16) char lds[32768];   // A tile 16KB | B tile 16KB
    __shared__ float redw[4];

    int wg = blockIdx.x;
    int rank = (wg & 7) * (NBLK / 8) + (wg >> 3);
    // decode rank -> (by, bx) in the upper triangle (by <= bx), row-major
    int by = (int)((129.0f - sqrtf(16641.0f - 8.0f * (float)rank)) * 0.5f);
    while (tri_cum(by + 1) <= rank) ++by;
    while (tri_cum(by) > rank) --by;
    int bx = by + (rank - tri_cum(by));

    int t = threadIdx.x;
    int rowBase = by * 128, colBase = bx * 128;
    int lane = t & 63, w = t >> 6;
    int wr = w >> 1, wc = w & 1;

    f32x4 acc[4][4];
    #pragma unroll
    for (int m = 0; m < 4; ++m)
        #pragma unroll
        for (int n = 0; n < 4; ++n) acc[m][n] = (f32x4)0.f;

    for (int ks = 0; ks < 12; ++ks) {
        int pass = ks >> 2, kc = ks & 3;
        const __bf16* Am = (pass == 2) ? L : H;   // A: hi, hi, lo
        const __bf16* Bm = (pass == 1) ? L : H;   // B: hi, lo, hi
        __syncthreads();   // previous step's ds_reads done before overwrite
        #pragma unroll
        for (int q = 0; q < 4; ++q) {
            int p = w * 4096 + q * 1024 + lane * 16;     // linear LDS byte offset
            int row = p >> 7;                            // 128B per row (64 bf16)
            int lcol = (p & 127) ^ ((row & 7) << 4);     // inverse-swizzled source col
            const char* ga = (const char*)Am + ((size_t)(rowBase + row) * 512 + kc * 128 + lcol);
            const char* gb = (const char*)Bm + ((size_t)(colBase + row) * 512 + kc * 128 + lcol);
            __builtin_amdgcn_global_load_lds(
                (const __attribute__((address_space(1))) void*)ga,
                (__attribute__((address_space(3))) void*)(lds + p), 16, 0, 0);
            __builtin_amdgcn_global_load_lds(
                (const __attribute__((address_space(1))) void*)gb,
                (__attribute__((address_space(3))) void*)(lds + 16384 + p), 16, 0, 0);
        }
        __syncthreads();   // compiler drains vmcnt(0) before barrier
        #pragma unroll
        for (int kk = 0; kk < 2; ++kk) {
            int kbyte = kk * 64 + (lane >> 4) * 16;
            bf16x8 af[4], bf[4];
            #pragma unroll
            for (int m = 0; m < 4; ++m) {
                int row = wr * 64 + m * 16 + (lane & 15);
                int off = ((row << 7) + kbyte) ^ ((row & 7) << 4);
                af[m] = *(const bf16x8*)(lds + off);
            }
            #pragma unroll
            for (int n = 0; n < 4; ++n) {
                int row = wc * 64 + n * 16 + (lane & 15);
                int off = ((row << 7) + kbyte) ^ ((row & 7) << 4);
                bf[n] = *(const bf16x8*)(lds + 16384 + off);
            }
            #pragma unroll
            for (int m = 0; m < 4; ++m)
                #pragma unroll
                for (int n = 0; n < 4; ++n)
                    acc[m][n] = __builtin_amdgcn_mfma_f32_16x16x32_bf16(
                        af[m], bf[n], acc[m][n], 0, 0, 0);
        }
    }

    // Fused epilogue: e4 = exp2(-dist*q); e3..e0 by repeated squaring.
    float q = qc[0], twoq = 2.f * q;
    int rsub = (lane >> 4) * 4, csub = lane & 15;
    float nqa[4][4], qb[4];
    #pragma unroll
    for (int m = 0; m < 4; ++m)
        #pragma unroll
        for (int r = 0; r < 4; ++r)
            nqa[m][r] = -q * sq[rowBase + wr * 64 + m * 16 + rsub + r];
    #pragma unroll
    for (int n = 0; n < 4; ++n)
        qb[n] = q * sq[colBase + wc * 64 + n * 16 + csub];

    float psum = 0.f;
    #pragma unroll
    for (int m = 0; m < 4; ++m) {
        #pragma unroll
        for (int n = 0; n < 4; ++n) {
            #pragma unroll
            for (int r = 0; r < 4; ++r) {
                float arg = fmaf(acc[m][n][r], twoq, nqa[m][r] - qb[n]);
                float e4 = __builtin_amdgcn_exp2f(arg);
                float e3 = e4 * e4, e2 = e3 * e3, e1 = e2 * e2, e0 = e1 * e1;
                psum += ((e4 + e3) + (e2 + e1)) + e0;
            }
        }
    }

    // Wave shuffle reduce, then tiny cross-wave combine (1 barrier).
    #pragma unroll
    for (int off = 32; off > 0; off >>= 1) psum += __shfl_xor(psum, off);
    if (lane == 0) redw[w] = psum;
    __syncthreads();
    if (t == 0) {
        float sign = ((rowBase < NHALF) == (colBase < NHALF)) ? 1.f : -1.f;
        float wgt = (bx == by) ? 1.f : 2.f;
        partials[rank] = sign * wgt * (redw[0] + redw[1] + redw[2] + redw[3]);
    }
}

// Pass 4: fp64 reduction of block partials -> final scalar.
__global__ void finalize_kernel(const float* __restrict__ partials, int n,
                                float* __restrict__ out)
{
    __shared__ double red[256];
    int t = threadIdx.x;
    double s = 0;
    for (int i = t; i < n; i += 256) s += (double)partials[i];
    red[t] = s;
    __syncthreads();
    for (int k = 128; k > 0; k >>= 1) { if (t < k) red[t] += red[t + k]; __syncthreads(); }
    if (t == 0) {
        double nn = (double)NHALF;
        out[0] = (float)(red[0] / 5.0 / (2.0 * nn * nn));
    }
}

extern "C" void kernel_launch(void* const* d_in, const int* in_sizes, int n_in,
                              void* d_out, int out_size, void* d_ws, size_t ws_size,
                              hipStream_t stream) {
    const float* src = (const float*)d_in[0];
    const float* tgt = (const float*)d_in[1];
    float* out = (float*)d_out;
    char* ws = (char*)d_ws;

    // ws layout (~8.6 MB total):
    float*  colpart  = (float*)(ws + 0);        // 256*256*4 = 256 KB
    float*  sqpart   = (float*)(ws + 262144);   // 256*4
    float*  qconst   = (float*)(ws + 263168);   // 4
    float*  sq       = (float*)(ws + 264192);   // 8192*4 = 32 KB
    float*  partials = (float*)(ws + 297984);   // 2080*4
    __bf16* H        = (__bf16*)(ws + 524288);  // 8192*256*2 = 4 MB
    __bf16* L        = (__bf16*)(ws + 4718592); // 4 MB

    prep_kernel<<<NB_PREP, 256, 0, stream>>>(src, tgt, H, L, sq, colpart, sqpart);
    bw_kernel<<<1, 256, 0, stream>>>(colpart, sqpart, qconst);
    mmd_main_kernel<<<NBLK, 256, 0, stream>>>(H, L, sq, qconst, partials);
    finalize_kernel<<<1, 256, 0, stream>>>(partials, NBLK, out);
}

// Round 4
// 51.135 us; speedup vs baseline: 6.8071x; 2.1630x over previous
//
#include <hip/hip_runtime.h>

#define NROWS 8192
#define NHALF 4096
#define DIM   256
#define NB_PREP 256
#define NTILES  64            // 8192 / 128
#define NBLK    2080          // NTILES*(NTILES+1)/2 upper-triangular blocks

typedef __attribute__((ext_vector_type(4))) float f32x4;

__device__ __forceinline__ const float* side_base(const float* src, const float* tgt, int row) {
    return (row < NHALF) ? (src + (size_t)row * DIM)
                         : (tgt + (size_t)(row - NHALF) * DIM);
}

// Pass 1: fp32 -> fp8 e4m3 quantized copy F8; per-row sumsq sq[] (fp32, exact);
// per-block column-sum partials + sumsq partials for the bandwidth identity.
__global__ __launch_bounds__(256) void prep_kernel(
        const float* __restrict__ src, const float* __restrict__ tgt,
        unsigned char* __restrict__ F8,
        float* __restrict__ sq, float* __restrict__ colpart, float* __restrict__ sqpart)
{
    int t = threadIdx.x;
    int lane = t & 63;
    int w = t >> 6;
    int wave = blockIdx.x * 4 + w;
    float cs0 = 0, cs1 = 0, cs2 = 0, cs3 = 0;
    double lss = 0.0;
    for (int r = wave; r < NROWS; r += NB_PREP * 4) {
        const float* p = side_base(src, tgt, r);
        float4 v = *(const float4*)(p + 4 * lane);
        cs0 += v.x; cs1 += v.y; cs2 += v.z; cs3 += v.w;
        // pack 4 fp8 (RNE, OCP e4m3). Byte order within the word is a uniform
        // K-permutation across all rows -> dot products unaffected.
        int p01 = __builtin_amdgcn_cvt_pk_fp8_f32(v.x, v.y, 0, false);
        int pk  = __builtin_amdgcn_cvt_pk_fp8_f32(v.z, v.w, p01, true);
        *(unsigned*)(F8 + (size_t)r * DIM + 4 * lane) = (unsigned)pk;
        float d = v.x * v.x + v.y * v.y + v.z * v.z + v.w * v.w;
        #pragma unroll
        for (int off = 32; off > 0; off >>= 1) d += __shfl_xor(d, off);
        if (lane == 0) { sq[r] = d; lss += (double)d; }
    }
    __shared__ float csh[4][256];
    __shared__ double ssh[4];
    csh[w][4 * lane + 0] = cs0; csh[w][4 * lane + 1] = cs1;
    csh[w][4 * lane + 2] = cs2; csh[w][4 * lane + 3] = cs3;
    if (lane == 0) ssh[w] = lss;
    __syncthreads();
    colpart[blockIdx.x * 256 + t] = csh[0][t] + csh[1][t] + csh[2][t] + csh[3][t];
    if (t == 0) sqpart[blockIdx.x] = (float)(ssh[0] + ssh[1] + ssh[2] + ssh[3]);
}

// Pass 2 (tiny): bandwidth via sum(dist) = 2*ns*sumsq - 2*||colsum||^2 (fp64),
// then the single exp2 constant q = log2(e) / (16*bw).
__global__ void bw_kernel(const float* __restrict__ colpart,
                          const float* __restrict__ sqpart, float* __restrict__ qconst)
{
    __shared__ double red[256], red2[256];
    int t = threadIdx.x;
    double s = 0;
    for (int b = 0; b < NB_PREP; ++b) s += (double)colpart[b * 256 + t];
    red[t] = s * s;
    red2[t] = (double)sqpart[t];   // NB_PREP == 256
    __syncthreads();
    for (int k = 128; k > 0; k >>= 1) {
        if (t < k) { red[t] += red[t + k]; red2[t] += red2[t + k]; }
        __syncthreads();
    }
    if (t == 0) {
        double ns = (double)NROWS;
        double sumdist = 2.0 * ns * red2[0] - 2.0 * red[0];
        double bw = sumdist / (ns * ns - ns) / 4.0;   // KERNEL_MUL^(KERNEL_NUM//2)=4
        qconst[0] = (float)(1.4426950408889634 / (16.0 * bw));
    }
}

__device__ __forceinline__ int tri_cum(int b) {   // # tiles before row b
    return b * NTILES - ((b * (b - 1)) >> 1);
}

// Pass 3: single-pass fp8 MFMA Gram GEMM with fused MMD epilogue.
// 128x128 tile / 4 waves (2x2) / 16x16x32 fp8 MFMA / full K=256 staged once
// (A 32KB + B 32KB LDS, XOR-swizzled, no mid-loop barriers).
__global__ __launch_bounds__(256) void mmd_main_kernel(
        const unsigned char* __restrict__ F8,
        const float* __restrict__ sq, const float* __restrict__ qc,
        float* __restrict__ partials)
{
    __shared__ alignas(16) char lds[65536];   // A tile 32KB | B tile 32KB

    int wg = blockIdx.x;
    int rank = (wg & 7) * (NBLK / 8) + (wg >> 3);
    // decode rank -> (by, bx) in the upper triangle (by <= bx), row-major
    int by = (int)((129.0f - sqrtf(16641.0f - 8.0f * (float)rank)) * 0.5f);
    while (tri_cum(by + 1) <= rank) ++by;
    while (tri_cum(by) > rank) --by;
    int bx = by + (rank - tri_cum(by));

    int t = threadIdx.x;
    int rowBase = by * 128, colBase = bx * 128;
    int lane = t & 63, w = t >> 6;
    int wr = w >> 1, wc = w & 1;

    // Stage both full-K tiles: 128 rows x 256 B each, linear LDS dest,
    // inverse-swizzled global source (involution: byte ^ ((row&7)<<4)).
    #pragma unroll
    for (int q = 0; q < 8; ++q) {
        int p = q * 4096 + t * 16;                 // linear LDS byte offset
        int row = p >> 8;                          // 256 B per row
        int col = (p & 255) ^ ((row & 7) << 4);
        const char* ga = (const char*)F8 + (((size_t)(rowBase + row)) << 8) + col;
        const char* gb = (const char*)F8 + (((size_t)(colBase + row)) << 8) + col;
        __builtin_amdgcn_global_load_lds(
            (const __attribute__((address_space(1))) void*)ga,
            (__attribute__((address_space(3))) void*)(lds + p), 16, 0, 0);
        __builtin_amdgcn_global_load_lds(
            (const __attribute__((address_space(1))) void*)gb,
            (__attribute__((address_space(3))) void*)(lds + 32768 + p), 16, 0, 0);
    }
    __syncthreads();   // compiler drains vmcnt(0) before barrier

    f32x4 acc[4][4];
    #pragma unroll
    for (int m = 0; m < 4; ++m)
        #pragma unroll
        for (int n = 0; n < 4; ++n) acc[m][n] = (f32x4)0.f;

    #pragma unroll
    for (int kk = 0; kk < 8; ++kk) {
        int kcol = kk * 32 + ((lane >> 4) << 3);   // 8 contiguous fp8 per lane
        long long af[4], bf[4];
        #pragma unroll
        for (int m = 0; m < 4; ++m) {
            int r = wr * 64 + m * 16 + (lane & 15);
            int off = ((r << 8) + kcol) ^ ((r & 7) << 4);
            af[m] = *(const long long*)(lds + off);
        }
        #pragma unroll
        for (int n = 0; n < 4; ++n) {
            int r = wc * 64 + n * 16 + (lane & 15);
            int off = ((r << 8) + kcol) ^ ((r & 7) << 4);
            bf[n] = *(const long long*)(lds + 32768 + off);
        }
        #pragma unroll
        for (int m = 0; m < 4; ++m)
            #pragma unroll
            for (int n = 0; n < 4; ++n)
                acc[m][n] = __builtin_amdgcn_mfma_f32_16x16x32_fp8_fp8(
                    af[m], bf[n], acc[m][n], 0, 0, 0);
    }

    // Fused epilogue: e4 = exp2(-dist*q); e3..e0 by repeated squaring.
    float q = qc[0], twoq = 2.f * q;
    int rsub = (lane >> 4) * 4, csub = lane & 15;
    float nqa[4][4], qb[4];
    #pragma unroll
    for (int m = 0; m < 4; ++m)
        #pragma unroll
        for (int r = 0; r < 4; ++r)
            nqa[m][r] = -q * sq[rowBase + wr * 64 + m * 16 + rsub + r];
    #pragma unroll
    for (int n = 0; n < 4; ++n)
        qb[n] = q * sq[colBase + wc * 64 + n * 16 + csub];

    float psum = 0.f;
    #pragma unroll
    for (int m = 0; m < 4; ++m) {
        #pragma unroll
        for (int n = 0; n < 4; ++n) {
            #pragma unroll
            for (int r = 0; r < 4; ++r) {
                float arg = fmaf(acc[m][n][r], twoq, nqa[m][r] - qb[n]);
                float e4 = __builtin_amdgcn_exp2f(arg);
                float e3 = e4 * e4, e2 = e3 * e3, e1 = e2 * e2, e0 = e1 * e1;
                psum += ((e4 + e3) + (e2 + e1)) + e0;
            }
        }
    }

    // Wave shuffle reduce, then tiny cross-wave combine (reuse LDS).
    #pragma unroll
    for (int off = 32; off > 0; off >>= 1) psum += __shfl_xor(psum, off);
    __syncthreads();                       // all frag reads done; safe to reuse lds
    float* redw = (float*)lds;
    if (lane == 0) redw[w] = psum;
    __syncthreads();
    if (t == 0) {
        float sign = ((rowBase < NHALF) == (colBase < NHALF)) ? 1.f : -1.f;
        float wgt = (bx == by) ? 1.f : 2.f;
        partials[rank] = sign * wgt * (redw[0] + redw[1] + redw[2] + redw[3]);
    }
}

// Pass 4: fp64 reduction of block partials -> final scalar.
__global__ void finalize_kernel(const float* __restrict__ partials, int n,
                                float* __restrict__ out)
{
    __shared__ double red[256];
    int t = threadIdx.x;
    double s = 0;
    for (int i = t; i < n; i += 256) s += (double)partials[i];
    red[t] = s;
    __syncthreads();
    for (int k = 128; k > 0; k >>= 1) { if (t < k) red[t] += red[t + k]; __syncthreads(); }
    if (t == 0) {
        double nn = (double)NHALF;
        out[0] = (float)(red[0] / 5.0 / (2.0 * nn * nn));
    }
}

extern "C" void kernel_launch(void* const* d_in, const int* in_sizes, int n_in,
                              void* d_out, int out_size, void* d_ws, size_t ws_size,
                              hipStream_t stream) {
    const float* src = (const float*)d_in[0];
    const float* tgt = (const float*)d_in[1];
    float* out = (float*)d_out;
    char* ws = (char*)d_ws;

    // ws layout (~2.6 MB total):
    float*         colpart  = (float*)(ws + 0);        // 256*256*4 = 256 KB
    float*         sqpart   = (float*)(ws + 262144);   // 256*4
    float*         qconst   = (float*)(ws + 263168);   // 4
    float*         sq       = (float*)(ws + 264192);   // 8192*4 = 32 KB
    float*         partials = (float*)(ws + 297984);   // 2080*4
    unsigned char* F8       = (unsigned char*)(ws + 524288);  // 8192*256 = 2 MB

    prep_kernel<<<NB_PREP, 256, 0, stream>>>(src, tgt, F8, sq, colpart, sqpart);
    bw_kernel<<<1, 256, 0, stream>>>(colpart, sqpart, qconst);
    mmd_main_kernel<<<NBLK, 256, 0, stream>>>(F8, sq, qconst, partials);
    finalize_kernel<<<1, 256, 0, stream>>>(partials, NBLK, out);
}

// Round 5
// 46.859 us; speedup vs baseline: 7.4282x; 1.0912x over previous
//
#include <hip/hip_runtime.h>

#define NROWS 8192
#define NHALF 4096
#define DIM   256
#define NB_PREP 256
#define NTILES  64            // 8192 / 128
#define NBLK    2080          // NTILES*(NTILES+1)/2 upper-triangular blocks

typedef __attribute__((ext_vector_type(4))) float f32x4;
typedef __attribute__((ext_vector_type(4))) int   v4i;
typedef __attribute__((ext_vector_type(8))) int   v8i;

__device__ __forceinline__ const float* side_base(const float* src, const float* tgt, int row) {
    return (row < NHALF) ? (src + (size_t)row * DIM)
                         : (tgt + (size_t)(row - NHALF) * DIM);
}

// Pass 1: fp32 -> fp8 e4m3 quantized copy F8; per-row sumsq sq[] (fp32, exact);
// per-block column-sum partials + sumsq partials for the bandwidth identity.
__global__ __launch_bounds__(256) void prep_kernel(
        const float* __restrict__ src, const float* __restrict__ tgt,
        unsigned char* __restrict__ F8,
        float* __restrict__ sq, float* __restrict__ colpart, float* __restrict__ sqpart)
{
    int t = threadIdx.x;
    int lane = t & 63;
    int w = t >> 6;
    int wave = blockIdx.x * 4 + w;
    float cs0 = 0, cs1 = 0, cs2 = 0, cs3 = 0;
    double lss = 0.0;
    for (int r = wave; r < NROWS; r += NB_PREP * 4) {
        const float* p = side_base(src, tgt, r);
        float4 v = *(const float4*)(p + 4 * lane);
        cs0 += v.x; cs1 += v.y; cs2 += v.z; cs3 += v.w;
        int p01 = __builtin_amdgcn_cvt_pk_fp8_f32(v.x, v.y, 0, false);
        int pk  = __builtin_amdgcn_cvt_pk_fp8_f32(v.z, v.w, p01, true);
        *(unsigned*)(F8 + (size_t)r * DIM + 4 * lane) = (unsigned)pk;
        float d = v.x * v.x + v.y * v.y + v.z * v.z + v.w * v.w;
        #pragma unroll
        for (int off = 32; off > 0; off >>= 1) d += __shfl_xor(d, off);
        if (lane == 0) { sq[r] = d; lss += (double)d; }
    }
    __shared__ float csh[4][256];
    __shared__ double ssh[4];
    csh[w][4 * lane + 0] = cs0; csh[w][4 * lane + 1] = cs1;
    csh[w][4 * lane + 2] = cs2; csh[w][4 * lane + 3] = cs3;
    if (lane == 0) ssh[w] = lss;
    __syncthreads();
    colpart[blockIdx.x * 256 + t] = csh[0][t] + csh[1][t] + csh[2][t] + csh[3][t];
    if (t == 0) sqpart[blockIdx.x] = (float)(ssh[0] + ssh[1] + ssh[2] + ssh[3]);
}

// Pass 2 (tiny): bandwidth via sum(dist) = 2*ns*sumsq - 2*||colsum||^2 (fp64),
// then the single exp2 constant q = log2(e) / (16*bw).
__global__ void bw_kernel(const float* __restrict__ colpart,
                          const float* __restrict__ sqpart, float* __restrict__ qconst)
{
    __shared__ double red[256], red2[256];
    int t = threadIdx.x;
    double s = 0;
    for (int b = 0; b < NB_PREP; ++b) s += (double)colpart[b * 256 + t];
    red[t] = s * s;
    red2[t] = (double)sqpart[t];   // NB_PREP == 256
    __syncthreads();
    for (int k = 128; k > 0; k >>= 1) {
        if (t < k) { red[t] += red[t + k]; red2[t] += red2[t + k]; }
        __syncthreads();
    }
    if (t == 0) {
        double ns = (double)NROWS;
        double sumdist = 2.0 * ns * red2[0] - 2.0 * red[0];
        double bw = sumdist / (ns * ns - ns) / 4.0;   // KERNEL_MUL^(KERNEL_NUM//2)=4
        qconst[0] = (float)(1.4426950408889634 / (16.0 * bw));
    }
}

__device__ __forceinline__ int tri_cum(int b) {   // # tiles before row b
    return b * NTILES - ((b * (b - 1)) >> 1);
}

// Load one 32-byte (K=128 fp8) fragment from a swizzled 128x128B LDS tile.
__device__ __forceinline__ v8i load_frag(const char* base, int r, int kbase) {
    int sw = (r & 7) << 4;
    v4i lo = *(const v4i*)(base + (r << 7) + (kbase ^ sw));
    v4i hi = *(const v4i*)(base + (r << 7) + ((kbase + 16) ^ sw));
    v8i out;
    out[0] = lo[0]; out[1] = lo[1]; out[2] = lo[2]; out[3] = lo[3];
    out[4] = hi[0]; out[5] = hi[1]; out[6] = hi[2]; out[7] = hi[3];
    return out;
}

__device__ __forceinline__ f32x4 mfma_k128(v8i a, v8i b, f32x4 c) {
#if __has_builtin(__builtin_amdgcn_mfma_scale_f32_16x16x128_f8f6f4)
    // fp8 e4m3 A/B (fmt 0), all block scales = E8M0 127 = x1.0 -> exact fp8 dot.
    return __builtin_amdgcn_mfma_scale_f32_16x16x128_f8f6f4(
        a, b, c, 0, 0, 0, 0x7F7F7F7F, 0, 0x7F7F7F7F);
#else
    const long long* av = (const long long*)&a;
    const long long* bv = (const long long*)&b;
    #pragma unroll
    for (int i = 0; i < 4; ++i)
        c = __builtin_amdgcn_mfma_f32_16x16x32_fp8_fp8(av[i], bv[i], c, 0, 0, 0);
    return c;
#endif
}

// Pass 3: fp8 MFMA Gram GEMM with fused MMD epilogue.
// 128x128 tile / 4 waves (2x2) / MX-scaled 16x16x128 fp8 MFMA.
// K=256 in two 128-wide phases; 32KB LDS single buffer -> 4 blocks/CU.
__global__ __launch_bounds__(256, 4) void mmd_main_kernel(
        const unsigned char* __restrict__ F8,
        const float* __restrict__ sq, const float* __restrict__ qc,
        float* __restrict__ partials)
{
    __shared__ alignas(16) char lds[32768];   // A tile 16KB | B tile 16KB

    int wg = blockIdx.x;
    int rank = (wg & 7) * (NBLK / 8) + (wg >> 3);
    // decode rank -> (by, bx) in the upper triangle (by <= bx), row-major
    int by = (int)((129.0f - sqrtf(16641.0f - 8.0f * (float)rank)) * 0.5f);
    while (tri_cum(by + 1) <= rank) ++by;
    while (tri_cum(by) > rank) --by;
    int bx = by + (rank - tri_cum(by));

    int t = threadIdx.x;
    int rowBase = by * 128, colBase = bx * 128;
    int lane = t & 63, w = t >> 6;
    int wr = w >> 1, wc = w & 1;
    int kbase = (lane >> 4) << 5;     // 32B K-chunk per 16-lane group

    f32x4 acc[4][4];
    #pragma unroll
    for (int m = 0; m < 4; ++m)
        #pragma unroll
        for (int n = 0; n < 4; ++n) acc[m][n] = (f32x4)0.f;

    #pragma unroll
    for (int kc = 0; kc < 2; ++kc) {
        if (kc) __syncthreads();      // all phase-0 ds_reads done before overwrite
        // Stage A+B K-half tiles: 128 rows x 128 B each, linear LDS dest,
        // inverse-swizzled global source (involution: byte ^ ((row&7)<<4)).
        #pragma unroll
        for (int q = 0; q < 4; ++q) {
            int p = q * 4096 + t * 16;                 // linear LDS byte offset
            int row = p >> 7;                          // 128 B per row
            int col = (p & 127) ^ ((row & 7) << 4);
            const char* ga = (const char*)F8 + (((size_t)(rowBase + row)) << 8) + kc * 128 + col;
            const char* gb = (const char*)F8 + (((size_t)(colBase + row)) << 8) + kc * 128 + col;
            __builtin_amdgcn_global_load_lds(
                (const __attribute__((address_space(1))) void*)ga,
                (__attribute__((address_space(3))) void*)(lds + p), 16, 0, 0);
            __builtin_amdgcn_global_load_lds(
                (const __attribute__((address_space(1))) void*)gb,
                (__attribute__((address_space(3))) void*)(lds + 16384 + p), 16, 0, 0);
        }
        __syncthreads();   // compiler drains vmcnt(0) before barrier

        v8i bf[4];
        #pragma unroll
        for (int n = 0; n < 4; ++n)
            bf[n] = load_frag(lds + 16384, wc * 64 + n * 16 + (lane & 15), kbase);
        #pragma unroll
        for (int m = 0; m < 4; ++m) {
            v8i af = load_frag(lds, wr * 64 + m * 16 + (lane & 15), kbase);
            #pragma unroll
            for (int n = 0; n < 4; ++n)
                acc[m][n] = mfma_k128(af, bf[n], acc[m][n]);
        }
    }

    // Fused epilogue: e4 = exp2(-dist*q); e3..e0 by repeated squaring.
    float q = qc[0], twoq = 2.f * q;
    int rsub = (lane >> 4) * 4, csub = lane & 15;
    float nqa[4][4], qb[4];
    #pragma unroll
    for (int m = 0; m < 4; ++m)
        #pragma unroll
        for (int r = 0; r < 4; ++r)
            nqa[m][r] = -q * sq[rowBase + wr * 64 + m * 16 + rsub + r];
    #pragma unroll
    for (int n = 0; n < 4; ++n)
        qb[n] = q * sq[colBase + wc * 64 + n * 16 + csub];

    float psum = 0.f;
    #pragma unroll
    for (int m = 0; m < 4; ++m) {
        #pragma unroll
        for (int n = 0; n < 4; ++n) {
            #pragma unroll
            for (int r = 0; r < 4; ++r) {
                float arg = fmaf(acc[m][n][r], twoq, nqa[m][r] - qb[n]);
                float e4 = __builtin_amdgcn_exp2f(arg);
                float e3 = e4 * e4, e2 = e3 * e3, e1 = e2 * e2, e0 = e1 * e1;
                psum += ((e4 + e3) + (e2 + e1)) + e0;
            }
        }
    }

    // Wave shuffle reduce, then tiny cross-wave combine (reuse LDS).
    #pragma unroll
    for (int off = 32; off > 0; off >>= 1) psum += __shfl_xor(psum, off);
    __syncthreads();                       // all frag reads done; safe to reuse lds
    float* redw = (float*)lds;
    if (lane == 0) redw[w] = psum;
    __syncthreads();
    if (t == 0) {
        float sign = ((rowBase < NHALF) == (colBase < NHALF)) ? 1.f : -1.f;
        float wgt = (bx == by) ? 1.f : 2.f;
        partials[rank] = sign * wgt * (redw[0] + redw[1] + redw[2] + redw[3]);
    }
}

// Pass 4: fp64 reduction of block partials -> final scalar.
__global__ void finalize_kernel(const float* __restrict__ partials, int n,
                                float* __restrict__ out)
{
    __shared__ double red[256];
    int t = threadIdx.x;
    double s = 0;
    for (int i = t; i < n; i += 256) s += (double)partials[i];
    red[t] = s;
    __syncthreads();
    for (int k = 128; k > 0; k >>= 1) { if (t < k) red[t] += red[t + k]; __syncthreads(); }
    if (t == 0) {
        double nn = (double)NHALF;
        out[0] = (float)(red[0] / 5.0 / (2.0 * nn * nn));
    }
}

extern "C" void kernel_launch(void* const* d_in, const int* in_sizes, int n_in,
                              void* d_out, int out_size, void* d_ws, size_t ws_size,
                              hipStream_t stream) {
    const float* src = (const float*)d_in[0];
    const float* tgt = (const float*)d_in[1];
    float* out = (float*)d_out;
    char* ws = (char*)d_ws;

    // ws layout (~2.6 MB total):
    float*         colpart  = (float*)(ws + 0);        // 256*256*4 = 256 KB
    float*         sqpart   = (float*)(ws + 262144);   // 256*4
    float*         qconst   = (float*)(ws + 263168);   // 4
    float*         sq       = (float*)(ws + 264192);   // 8192*4 = 32 KB
    float*         partials = (float*)(ws + 297984);   // 2080*4
    unsigned char* F8       = (unsigned char*)(ws + 524288);  // 8192*256 = 2 MB

    prep_kernel<<<NB_PREP, 256, 0, stream>>>(src, tgt, F8, sq, colpart, sqpart);
    bw_kernel<<<1, 256, 0, stream>>>(colpart, sqpart, qconst);
    mmd_main_kernel<<<NBLK, 256, 0, stream>>>(F8, sq, qconst, partials);
    finalize_kernel<<<1, 256, 0, stream>>>(partials, NBLK, out);
}